// Round 1
// baseline (576.293 us; speedup 1.0000x reference)
//
#include <hip/hip_runtime.h>
#include <hip/hip_bf16.h>
#include <math.h>

// Problem constants (ProxyGML: B=1024, DIM=512, C=1000, N=8)
#define PB   1024
#define PDIM 512
#define PC   1000
#define PN   8
#define PCN  8000          // C*N
#define PTOPK 400
#define NONPOS_K 392       // TOPK - N (positives always selected)

// ---------------------------------------------------------------- norms ----
__global__ __launch_bounds__(256) void k_norm(const float* __restrict__ P,
                                              float* __restrict__ inv) {
    int j = blockIdx.x * 256 + threadIdx.x;
    if (j >= PCN) return;
    float ss = 0.f;
    for (int d = 0; d < PDIM; ++d) {
        float v = P[(size_t)d * PCN + j];
        ss = fmaf(v, v, ss);
    }
    float n = fmaxf(sqrtf(ss), 1e-12f);
    inv[j] = 1.0f / n;
}

// ---------------------------------------------------------------- GEMM1 ----
// sim[b,j] = inv[j] * sum_d x[b,d] * P[d,j]   (M=1024, N=8000, K=512)
#define BM 64
#define BN 64
#define BK 16
__global__ __launch_bounds__(256) void k_gemm1(const float* __restrict__ X,
                                               const float* __restrict__ P,
                                               const float* __restrict__ inv,
                                               float* __restrict__ sim) {
    __shared__ float As[BK][BM + 4];
    __shared__ float Bs[BK][BN];
    int tid = threadIdx.x;
    int n0 = blockIdx.x * BN;   // over CN (125 blocks)
    int m0 = blockIdx.y * BM;   // over B  (16 blocks)
    int tx = tid & 15, ty = tid >> 4;
    float acc[4][4] = {};
    for (int k0 = 0; k0 < PDIM; k0 += BK) {
        {   // A tile 64x16: x[(m0+i)*512 + k0+kk]
            int l = tid * 4;
            int i = l >> 4, kk = l & 15;
            float4 a4 = *(const float4*)(X + (size_t)(m0 + i) * PDIM + k0 + kk);
            As[kk + 0][i] = a4.x; As[kk + 1][i] = a4.y;
            As[kk + 2][i] = a4.z; As[kk + 3][i] = a4.w;
        }
        {   // B tile 16x64: P[(k0+kk)*8000 + n0+jj]
            int l = tid * 4;
            int kk = l >> 6, jj = l & 63;
            *(float4*)&Bs[kk][jj] =
                *(const float4*)(P + (size_t)(k0 + kk) * PCN + n0 + jj);
        }
        __syncthreads();
#pragma unroll
        for (int k = 0; k < BK; ++k) {
            float av[4], bv[4];
            *(float4*)av = *(const float4*)&As[k][ty * 4];
            *(float4*)bv = *(const float4*)&Bs[k][tx * 4];
#pragma unroll
            for (int u = 0; u < 4; ++u)
#pragma unroll
                for (int v = 0; v < 4; ++v)
                    acc[u][v] = fmaf(av[u], bv[v], acc[u][v]);
        }
        __syncthreads();
    }
    float4 iv = *(const float4*)(inv + n0 + tx * 4);
#pragma unroll
    for (int u = 0; u < 4; ++u) {
        float4 o;
        o.x = acc[u][0] * iv.x; o.y = acc[u][1] * iv.y;
        o.z = acc[u][2] * iv.z; o.w = acc[u][3] * iv.w;
        *(float4*)(sim + (size_t)(m0 + ty * 4 + u) * PCN + n0 + tx * 4) = o;
    }
}

// ------------------------------------------------------------- row loss ----
// Per row b: tau = 392nd largest among non-positive sims (bisection),
// logits per class from selected sims, softmax loss with reference epsilons.
__global__ __launch_bounds__(256) void k_rowloss(const float* __restrict__ sim,
                                                 const int* __restrict__ target,
                                                 float* __restrict__ acc) {
    __shared__ float s[PCN];
    __shared__ int   redi[4];
    __shared__ int   redi2[8];
    __shared__ float redf[4];
    __shared__ float s_et;
    int b = blockIdx.x, tid = threadIdx.x;
    const float* row = sim + (size_t)b * PCN;
    for (int j = tid; j < PCN; j += 256) s[j] = row[j];
    int targ = target[b];
    __syncthreads();

    // bisection for tau
    float lo = -64.f, hi = 64.f;
    for (int it = 0; it < 50; ++it) {
        float mid = 0.5f * (lo + hi);
        int cnt = 0;
        for (int j = tid; j < PCN; j += 256)
            cnt += ((j >> 3) != targ && s[j] >= mid) ? 1 : 0;
        for (int off = 32; off; off >>= 1) cnt += __shfl_down(cnt, off, 64);
        __syncthreads();               // protect redi from previous read
        if ((tid & 63) == 0) redi[tid >> 6] = cnt;
        __syncthreads();
        cnt = redi[0] + redi[1] + redi[2] + redi[3];
        if (cnt >= NONPOS_K) lo = mid; else hi = mid;
    }
    float tau = lo;

    // strict-greater and equal counts among non-positives
    int cgt = 0, ceq = 0;
    for (int j = tid; j < PCN; j += 256) {
        if ((j >> 3) != targ) {
            float v = s[j];
            cgt += (v > tau) ? 1 : 0;
            ceq += (v == tau) ? 1 : 0;
        }
    }
    for (int off = 32; off; off >>= 1) {
        cgt += __shfl_down(cgt, off, 64);
        ceq += __shfl_down(ceq, off, 64);
    }
    __syncthreads();
    if ((tid & 63) == 0) { redi2[tid >> 6] = cgt; redi2[4 + (tid >> 6)] = ceq; }
    __syncthreads();
    cgt = redi2[0] + redi2[1] + redi2[2] + redi2[3];
    ceq = redi2[4] + redi2[5] + redi2[6] + redi2[7];
    int rem = NONPOS_K - cgt;          // equals to include (index order)
    bool all_eq = (rem >= ceq);

    // per-class logits -> exp -> partial sums
    float psum = 0.f;
    for (int c = tid; c < PC; c += 256) {
        float lg = 0.f;
        float4 p0 = *(const float4*)&s[c * 8];
        float4 p1 = *(const float4*)&s[c * 8 + 4];
        float pv[8] = {p0.x, p0.y, p0.z, p0.w, p1.x, p1.y, p1.z, p1.w};
        if (c == targ) {
#pragma unroll
            for (int n = 0; n < 8; ++n) lg += pv[n];
        } else {
#pragma unroll
            for (int n = 0; n < 8; ++n) {
                float v = pv[n];
                bool sel = v > tau;
                if (!sel && v == tau) {
                    if (all_eq) sel = true;
                    else {       // rare tie path: rank among equals by index
                        int rank = 0, j = c * 8 + n;
                        for (int jj = 0; jj < j; ++jj)
                            rank += ((jj >> 3) != targ && s[jj] == tau) ? 1 : 0;
                        sel = (rank < rem);
                    }
                }
                if (sel) lg += v;
            }
        }
        float e = (lg != 0.0f) ? expf(lg) : 0.0f;
        psum += e;
        if (c == targ) s_et = e;
    }
    for (int off = 32; off; off >>= 1) psum += __shfl_down(psum, off, 64);
    if ((tid & 63) == 0) redf[tid >> 6] = psum;
    __syncthreads();
    if (tid == 0) {
        float denom = 1e-8f + redf[0] + redf[1] + redf[2] + redf[3];
        float pt = s_et / denom;
        float lb = -logf(pt + 1e-20f);
        atomicAdd(acc, lb);
    }
}

// ------------------------------------------------------------- centers_cls -
// ccls[d,c] = sum_n P[d, c*8+n] * inv[c*8+n]
__global__ __launch_bounds__(256) void k_ccls(const float* __restrict__ P,
                                              const float* __restrict__ inv,
                                              float* __restrict__ ccls) {
    int idx = blockIdx.x * 256 + threadIdx.x;
    if (idx >= PDIM * PC) return;
    int d = idx / PC, c = idx - d * PC;
    const float* p  = P + (size_t)d * PCN + c * 8;
    const float* iv = inv + c * 8;
    float sacc = 0.f;
#pragma unroll
    for (int n = 0; n < 8; ++n) sacc = fmaf(p[n], iv[n], sacc);
    ccls[idx] = sacc;
}

// ---------------------------------------------------------------- GEMM2 ----
// clog[j,c] = inv[j] * sum_d P[d,j] * ccls[d,c]  (M=8000, N=1000, K=512)
__global__ __launch_bounds__(256) void k_gemm2(const float* __restrict__ P,
                                               const float* __restrict__ ccls,
                                               const float* __restrict__ inv,
                                               float* __restrict__ clog) {
    __shared__ float As[BK][BM + 4];
    __shared__ float Bs[BK][BN];
    int tid = threadIdx.x;
    int c0 = blockIdx.x * BN;   // over C (16 blocks, guarded)
    int j0 = blockIdx.y * BM;   // over CN (125 blocks)
    int tx = tid & 15, ty = tid >> 4;
    float acc[4][4] = {};
    for (int k0 = 0; k0 < PDIM; k0 += BK) {
        {   // A tile: P[(k0+kk)*8000 + j0+i] (transposed source, contiguous j)
            int l = tid * 4;
            int kk = l >> 6, i = l & 63;
            *(float4*)&As[kk][i] =
                *(const float4*)(P + (size_t)(k0 + kk) * PCN + j0 + i);
        }
        {   // B tile: ccls[(k0+kk)*1000 + c0+jj], guarded at c>=1000
            int l = tid * 4;
            int kk = l >> 6, jj = l & 63;
            float bb[4];
#pragma unroll
            for (int q = 0; q < 4; ++q) {
                int cc = c0 + jj + q;
                bb[q] = (cc < PC) ? ccls[(size_t)(k0 + kk) * PC + cc] : 0.f;
            }
            *(float4*)&Bs[kk][jj] = *(float4*)bb;
        }
        __syncthreads();
#pragma unroll
        for (int k = 0; k < BK; ++k) {
            float av[4], bv[4];
            *(float4*)av = *(const float4*)&As[k][ty * 4];
            *(float4*)bv = *(const float4*)&Bs[k][tx * 4];
#pragma unroll
            for (int u = 0; u < 4; ++u)
#pragma unroll
                for (int v = 0; v < 4; ++v)
                    acc[u][v] = fmaf(av[u], bv[v], acc[u][v]);
        }
        __syncthreads();
    }
#pragma unroll
    for (int u = 0; u < 4; ++u) {
        int j = j0 + ty * 4 + u;
        float sc = inv[j];
#pragma unroll
        for (int v = 0; v < 4; ++v) {
            int c = c0 + tx * 4 + v;
            if (c < PC) clog[(size_t)j * PC + c] = acc[u][v] * sc;
        }
    }
}

// --------------------------------------------------------------- reg row ---
// reg_j = logsumexp(clog[j,:]) - clog[j, j/8]
__global__ __launch_bounds__(256) void k_reg(const float* __restrict__ clog,
                                             float* __restrict__ acc) {
    __shared__ float rmax[4];
    __shared__ float rsum[4];
    __shared__ float s_mx;
    int j = blockIdx.x, tid = threadIdx.x;
    const float* row = clog + (size_t)j * PC;
    float v[4];
    float mx = -INFINITY;
#pragma unroll
    for (int k = 0; k < 4; ++k) {
        int c = tid + k * 256;
        v[k] = (c < PC) ? row[c] : -INFINITY;
        mx = fmaxf(mx, v[k]);
    }
    for (int off = 32; off; off >>= 1) mx = fmaxf(mx, __shfl_down(mx, off, 64));
    if ((tid & 63) == 0) rmax[tid >> 6] = mx;
    __syncthreads();
    if (tid == 0) s_mx = fmaxf(fmaxf(rmax[0], rmax[1]), fmaxf(rmax[2], rmax[3]));
    __syncthreads();
    float m = s_mx;
    float sum = 0.f;
#pragma unroll
    for (int k = 0; k < 4; ++k)
        if (tid + k * 256 < PC) sum += expf(v[k] - m);
    for (int off = 32; off; off >>= 1) sum += __shfl_down(sum, off, 64);
    if ((tid & 63) == 0) rsum[tid >> 6] = sum;
    __syncthreads();
    if (tid == 0) {
        float S = rsum[0] + rsum[1] + rsum[2] + rsum[3];
        float lse = logf(S) + m;
        atomicAdd(acc + 1, lse - row[j >> 3]);
    }
}

// --------------------------------------------------------------- finalize --
__global__ void k_final(const float* __restrict__ acc, float* __restrict__ out) {
    float lc = acc[0] * (1.0f / PB);
    float rg = acc[1] * (1.0f / PCN);
    out[0] = lc + 0.3f * rg;   // total
    out[1] = lc;               // loss_classify
}

// ---------------------------------------------------------------------------
extern "C" void kernel_launch(void* const* d_in, const int* in_sizes, int n_in,
                              void* d_out, int out_size, void* d_ws, size_t ws_size,
                              hipStream_t stream) {
    const float* x       = (const float*)d_in[0];   // (1024, 512)
    const float* proxies = (const float*)d_in[1];   // (512, 8000)
    const int*   target  = (const int*)d_in[2];     // (1024,)
    float* out = (float*)d_out;
    float* ws  = (float*)d_ws;

    // workspace layout (floats):
    float* acc  = ws;                    // [2]   loss_sum, reg_sum
    float* inv  = ws + 64;               // [8000]
    float* ccls = ws + 64 + 8192;        // [512000]
    float* big  = ws + 64 + 8192 + 512000; // [8192000] sim, then aliased clog
    // total: 8,712,256 floats = 34.85 MB

    hipMemsetAsync(acc, 0, 2 * sizeof(float), stream);

    k_norm<<<(PCN + 255) / 256, 256, 0, stream>>>(proxies, inv);

    dim3 g1(PCN / BN, PB / BM);          // (125, 16)
    k_gemm1<<<g1, 256, 0, stream>>>(x, proxies, inv, big);

    k_rowloss<<<PB, 256, 0, stream>>>(big, target, acc);

    k_ccls<<<(PDIM * PC + 255) / 256, 256, 0, stream>>>(proxies, inv, ccls);

    dim3 g2((PC + BN - 1) / BN, PCN / BM);   // (16, 125)
    k_gemm2<<<g2, 256, 0, stream>>>(proxies, ccls, inv, big);

    k_reg<<<PCN, 256, 0, stream>>>(big, acc);

    k_final<<<1, 1, 0, stream>>>(acc, out);
}

// Round 2
// 199.904 us; speedup vs baseline: 2.8828x; 2.8828x over previous
//
#include <hip/hip_runtime.h>
#include <hip/hip_bf16.h>
#include <math.h>

// ProxyGML: B=1024, DIM=512, C=1000, N=8
#define PB   1024
#define PDIM 512
#define PC   1000
#define PN   8
#define PCN  8000
#define PTOPK 400
#define NONPOS_K 392

typedef __bf16 bf16x8 __attribute__((ext_vector_type(8)));
typedef __bf16 bf16x4 __attribute__((ext_vector_type(4)));
typedef float  f32x4  __attribute__((ext_vector_type(4)));

__device__ static inline void async_load16(const __bf16* g, __bf16* l) {
    __builtin_amdgcn_global_load_lds(
        (const __attribute__((address_space(1))) void*)g,
        (__attribute__((address_space(3))) void*)l,
        16, 0, 0);
}

// ----------------------------------------------------- norm (partial) -----
// ssq[j] += sum over 64 d-rows of P[d,j]^2
__global__ __launch_bounds__(256) void k_norm_part(const float* __restrict__ P,
                                                   float* __restrict__ ssq) {
    int j = blockIdx.x * 256 + threadIdx.x;
    if (j >= PCN) return;
    const float* p = P + (size_t)(blockIdx.y * 64) * PCN + j;
    float ss = 0.f;
#pragma unroll 8
    for (int r = 0; r < 64; ++r) {
        float v = p[(size_t)r * PCN];
        ss = fmaf(v, v, ss);
    }
    atomicAdd(&ssq[j], ss);
}

__global__ __launch_bounds__(256) void k_norm_fin(const float* __restrict__ ssq,
                                                  float* __restrict__ inv) {
    int j = blockIdx.x * 256 + threadIdx.x;
    if (j >= PCN) return;
    inv[j] = 1.0f / fmaxf(sqrtf(ssq[j]), 1e-12f);
}

// ----------------------------------------------------- x -> bf16 ----------
__global__ __launch_bounds__(256) void k_xconv(const float* __restrict__ x,
                                               __bf16* __restrict__ xb) {
    int i = blockIdx.x * 256 + threadIdx.x;   // 131072 float4 groups
    float4 v = ((const float4*)x)[i];
    bf16x4 o;
    o[0] = (__bf16)v.x; o[1] = (__bf16)v.y; o[2] = (__bf16)v.z; o[3] = (__bf16)v.w;
    ((bf16x4*)xb)[i] = o;
}

// ------------------------------------- P (512x8000) -> P_t bf16 (8000x512) -
// P_t[j][d] = P[d][j] * inv[j]
__global__ __launch_bounds__(256) void k_tpose(const float* __restrict__ P,
                                               const float* __restrict__ inv,
                                               __bf16* __restrict__ Pt) {
    __shared__ float t[64][65];
    int tid = threadIdx.x;
    int tx = tid & 63, ty = tid >> 6;
    int j0 = blockIdx.x * 64, d0 = blockIdx.y * 64;
#pragma unroll
    for (int r = 0; r < 16; ++r) {
        int d = d0 + ty * 16 + r;
        t[ty * 16 + r][tx] = P[(size_t)d * PCN + j0 + tx];
    }
    __syncthreads();
#pragma unroll
    for (int r = 0; r < 16; ++r) {
        int jl = ty * 16 + r;
        float val = t[tx][jl] * inv[j0 + jl];
        Pt[(size_t)(j0 + jl) * PDIM + d0 + tx] = (__bf16)val;
    }
}

// --------------------------------------------- ccls_t bf16 (1024x512) -----
// ccls[c][d] = sum_n Pt[c*8+n][d]; rows c>=1000 zeroed
__global__ __launch_bounds__(256) void k_ccls(const __bf16* __restrict__ Pt,
                                              __bf16* __restrict__ ccls) {
    int idx = blockIdx.x * 256 + threadIdx.x;   // 1024*512
    int d = idx & 511, c = idx >> 9;
    float s = 0.f;
    if (c < PC) {
#pragma unroll
        for (int n = 0; n < 8; ++n)
            s += (float)Pt[(size_t)(c * 8 + n) * PDIM + d];
    }
    ccls[idx] = (__bf16)s;
}

// ---------------------------------------------------------------- GEMM ----
// out[m][j] = sum_d A[m][d] * Pt[j][d]   (M=1024 compute, guard Mstore; N=8000)
// 128x128 tile, 256 thr (4 waves 2x2), BK=32, mfma 16x16x32 bf16, 4x4/wave
__global__ __launch_bounds__(256) void k_gemm(const __bf16* __restrict__ A,
                                              const __bf16* __restrict__ Bt,
                                              float* __restrict__ out,
                                              int Mstore) {
    __shared__ __bf16 As[128 * 32];
    __shared__ __bf16 Bs[128 * 32];
    int tid = threadIdx.x;
    int w = tid >> 6, lane = tid & 63;
    int wr = w >> 1, wc = w & 1;
    int quad = lane >> 4, l15 = lane & 15;
    int n0 = blockIdx.x * 128, m0 = blockIdx.y * 128;
    f32x4 acc[4][4] = {};
    for (int k0 = 0; k0 < PDIM; k0 += 32) {
#pragma unroll
        for (int pass = 0; pass < 2; ++pass) {
            int cbase = pass * 256 + w * 64;
            int c = cbase + lane;
            int arow = m0 + (c >> 2);
            async_load16(A + (size_t)arow * PDIM + k0 + (c & 3) * 8, &As[cbase * 8]);
            int brow = n0 + (c >> 2);
            if (brow > PCN - 1) brow = PCN - 1;
            async_load16(Bt + (size_t)brow * PDIM + k0 + (c & 3) * 8, &Bs[cbase * 8]);
        }
        __syncthreads();
        bf16x8 av[4], bv[4];
#pragma unroll
        for (int i = 0; i < 4; ++i) {
            av[i] = *(const bf16x8*)&As[(wr * 64 + i * 16 + l15) * 32 + quad * 8];
            bv[i] = *(const bf16x8*)&Bs[(wc * 64 + i * 16 + l15) * 32 + quad * 8];
        }
#pragma unroll
        for (int i = 0; i < 4; ++i)
#pragma unroll
            for (int j = 0; j < 4; ++j)
                acc[i][j] = __builtin_amdgcn_mfma_f32_16x16x32_bf16(
                    av[i], bv[j], acc[i][j], 0, 0, 0);
        __syncthreads();
    }
#pragma unroll
    for (int i = 0; i < 4; ++i) {
        int r0 = m0 + wr * 64 + i * 16 + quad * 4;
#pragma unroll
        for (int j = 0; j < 4; ++j) {
            int cc = n0 + wc * 64 + j * 16 + l15;
            if (cc < PCN) {
#pragma unroll
                for (int r = 0; r < 4; ++r) {
                    int rr = r0 + r;
                    if (rr < Mstore) out[(size_t)rr * PCN + cc] = acc[i][j][r];
                }
            }
        }
    }
}

// ------------------------------------------------------------- row loss ---
// Radix-select tau = 392nd-largest non-positive sim, then softmax loss.
__global__ __launch_bounds__(256) void k_rowloss(const float* __restrict__ sim,
                                                 const int* __restrict__ target,
                                                 float* __restrict__ acc) {
    __shared__ float s[PCN];
    __shared__ unsigned hist[256];
    __shared__ int sh_bin;
    __shared__ float redf[4];
    __shared__ float s_et;
    int b = blockIdx.x, tid = threadIdx.x;
    const float* row = sim + (size_t)b * PCN;
    int targ = target[b];
    for (int j = tid; j < PCN; j += 256) s[j] = row[j];
    __syncthreads();

    unsigned prefix = 0;
    int rank = NONPOS_K;   // rank within current prefix group (from top)
    int cgt = 0, ceq = 0;
    for (int pass = 0; pass < 4; ++pass) {
        int shift = 24 - pass * 8;
        hist[tid] = 0u;
        __syncthreads();
        for (int j = tid; j < PCN; j += 256) {
            if ((j >> 3) == targ) continue;
            unsigned u = __float_as_uint(s[j]);
            unsigned key = u ^ (unsigned)(((int)u >> 31) | 0x80000000);
            if (pass == 0 || (key >> (shift + 8)) == prefix)
                atomicAdd(&hist[(key >> shift) & 255], 1u);
        }
        __syncthreads();
        // suffix sum: hist[t] = count of digits >= t
        for (int step = 1; step < 256; step <<= 1) {
            unsigned v = (tid + step < 256) ? hist[tid + step] : 0u;
            __syncthreads();
            hist[tid] += v;
            __syncthreads();
        }
        unsigned sufd = hist[tid];
        unsigned sufn = (tid < 255) ? hist[tid + 1] : 0u;
        if (sufd >= (unsigned)rank && sufn < (unsigned)rank) sh_bin = tid;
        __syncthreads();
        int bin = sh_bin;
        unsigned above = (bin < 255) ? hist[bin + 1] : 0u;
        cgt += (int)above;
        rank -= (int)above;
        if (pass == 3) ceq = (int)(hist[bin] - above);
        prefix = (prefix << 8) | (unsigned)bin;
        __syncthreads();   // protect hist before next pass reset
    }
    unsigned tk = prefix;
    float tau = __uint_as_float((tk & 0x80000000u) ? (tk ^ 0x80000000u) : ~tk);
    int rem = rank;                 // equals (==tau) to include, by index order
    bool all_eq = (rem >= ceq);

    // per-class logits -> exp -> partial sums
    float psum = 0.f;
    for (int c = tid; c < PC; c += 256) {
        float lg = 0.f;
        float4 p0 = *(const float4*)&s[c * 8];
        float4 p1 = *(const float4*)&s[c * 8 + 4];
        float pv[8] = {p0.x, p0.y, p0.z, p0.w, p1.x, p1.y, p1.z, p1.w};
        if (c == targ) {
#pragma unroll
            for (int n = 0; n < 8; ++n) lg += pv[n];
        } else {
#pragma unroll
            for (int n = 0; n < 8; ++n) {
                float v = pv[n];
                bool sel = v > tau;
                if (!sel && v == tau) {
                    if (all_eq) sel = true;
                    else {
                        int rk = 0, j = c * 8 + n;
                        for (int jj = 0; jj < j; ++jj)
                            rk += ((jj >> 3) != targ && s[jj] == tau) ? 1 : 0;
                        sel = (rk < rem);
                    }
                }
                if (sel) lg += v;
            }
        }
        float e = (lg != 0.0f) ? expf(lg) : 0.0f;
        psum += e;
        if (c == targ) s_et = e;
    }
    for (int off = 32; off; off >>= 1) psum += __shfl_down(psum, off, 64);
    if ((tid & 63) == 0) redf[tid >> 6] = psum;
    __syncthreads();
    if (tid == 0) {
        float denom = 1e-8f + redf[0] + redf[1] + redf[2] + redf[3];
        float pt = s_et / denom;
        atomicAdd(acc, -logf(pt + 1e-20f));
    }
}

// ------------------------------------------------------------- reg --------
// clog_t is (1000 x 8000): reg_j = logsumexp_c(clog_t[c][j]) - clog_t[j>>3][j]
__global__ __launch_bounds__(256) void k_reg(const float* __restrict__ clog,
                                             float* __restrict__ acc) {
    __shared__ float sm[4][64], ssum[4][64];
    int tid = threadIdx.x;
    int jj = tid & 63, cg = tid >> 6;
    int j = blockIdx.x * 64 + jj;   // 125 blocks -> j < 8000
    float m = -INFINITY, sv = 0.f;
    for (int c = cg * 250; c < cg * 250 + 250; ++c) {
        float v = clog[(size_t)c * PCN + j];
        float nm = fmaxf(m, v);
        sv = sv * expf(m - nm) + expf(v - nm);
        m = nm;
    }
    sm[cg][jj] = m; ssum[cg][jj] = sv;
    __syncthreads();
    if (tid < 64) {
        float M = fmaxf(fmaxf(sm[0][tid], sm[1][tid]), fmaxf(sm[2][tid], sm[3][tid]));
        float S = ssum[0][tid] * expf(sm[0][tid] - M) + ssum[1][tid] * expf(sm[1][tid] - M)
                + ssum[2][tid] * expf(sm[2][tid] - M) + ssum[3][tid] * expf(sm[3][tid] - M);
        int j2 = blockIdx.x * 64 + tid;
        float val = logf(S) + M - clog[(size_t)(j2 >> 3) * PCN + j2];
        for (int off = 32; off; off >>= 1) val += __shfl_down(val, off, 64);
        if (tid == 0) atomicAdd(acc + 1, val);
    }
}

// --------------------------------------------------------------- final ----
__global__ void k_final(const float* __restrict__ acc, float* __restrict__ out) {
    float lc = acc[0] * (1.0f / PB);
    float rg = acc[1] * (1.0f / PCN);
    out[0] = lc + 0.3f * rg;
    out[1] = lc;
}

// ---------------------------------------------------------------------------
extern "C" void kernel_launch(void* const* d_in, const int* in_sizes, int n_in,
                              void* d_out, int out_size, void* d_ws, size_t ws_size,
                              hipStream_t stream) {
    const float* x       = (const float*)d_in[0];   // (1024, 512)
    const float* proxies = (const float*)d_in[1];   // (512, 8000)
    const int*   target  = (const int*)d_in[2];     // (1024,)
    float* out = (float*)d_out;
    float* ws  = (float*)d_ws;

    // workspace layout (float offsets)
    float*  acc   = ws;                       // [2] (+pad)
    float*  ssq   = ws + 64;                  // [8000]
    float*  inv   = ws + 64 + 8192;           // [8000]
    __bf16* xb    = (__bf16*)(ws + 16448);    // 1024x512 bf16
    __bf16* cclsb = (__bf16*)(ws + 278592);   // 1024x512 bf16
    __bf16* Pt    = (__bf16*)(ws + 540736);   // 8000x512 bf16
    float*  big   = ws + 2588736;             // 1024x8000 f32 (sim, then clog_t)
    // total: 10,780,736 floats = 41.1 MiB

    hipMemsetAsync(ws, 0, (64 + 8000) * sizeof(float), stream);   // acc + ssq

    k_norm_part<<<dim3(32, 8), 256, 0, stream>>>(proxies, ssq);
    k_norm_fin<<<32, 256, 0, stream>>>(ssq, inv);
    k_xconv<<<512, 256, 0, stream>>>(x, xb);
    k_tpose<<<dim3(125, 8), 256, 0, stream>>>(proxies, inv, Pt);
    k_ccls<<<2048, 256, 0, stream>>>(Pt, cclsb);

    k_gemm<<<dim3(63, 8), 256, 0, stream>>>(xb, Pt, big, 1024);   // sim
    k_rowloss<<<PB, 256, 0, stream>>>(big, target, acc);

    k_gemm<<<dim3(63, 8), 256, 0, stream>>>(cclsb, Pt, big, PC);  // clog_t
    k_reg<<<125, 256, 0, stream>>>(big, acc);

    k_final<<<1, 1, 0, stream>>>(acc, out);
}

// Round 3
// 181.114 us; speedup vs baseline: 3.1819x; 1.1037x over previous
//
#include <hip/hip_runtime.h>
#include <hip/hip_bf16.h>
#include <math.h>

// ProxyGML: B=1024, DIM=512, C=1000, N=8
#define PB   1024
#define PDIM 512
#define PC   1000
#define PN   8
#define PCN  8000
#define PTOPK 400
#define NONPOS_K 392
#define NBIN 1024
#define CANDMAX 256

typedef __bf16 bf16x8 __attribute__((ext_vector_type(8)));
typedef __bf16 bf16x4 __attribute__((ext_vector_type(4)));
typedef float  f32x4  __attribute__((ext_vector_type(4)));

__device__ static inline void async_load16(const __bf16* g, __bf16* l) {
    __builtin_amdgcn_global_load_lds(
        (const __attribute__((address_space(1))) void*)g,
        (__attribute__((address_space(3))) void*)l,
        16, 0, 0);
}

// ----------------------------------------------------- norm (partial) -----
__global__ __launch_bounds__(256) void k_norm_part(const float* __restrict__ P,
                                                   float* __restrict__ ssq) {
    int j = blockIdx.x * 256 + threadIdx.x;
    if (j >= PCN) return;
    const float* p = P + (size_t)(blockIdx.y * 64) * PCN + j;
    float ss = 0.f;
#pragma unroll 8
    for (int r = 0; r < 64; ++r) {
        float v = p[(size_t)r * PCN];
        ss = fmaf(v, v, ss);
    }
    atomicAdd(&ssq[j], ss);
}

// ----------------------------------------------------- x -> bf16 ----------
__global__ __launch_bounds__(256) void k_xconv(const float* __restrict__ x,
                                               __bf16* __restrict__ xb) {
    int i = blockIdx.x * 256 + threadIdx.x;
    float4 v = ((const float4*)x)[i];
    bf16x4 o;
    o[0] = (__bf16)v.x; o[1] = (__bf16)v.y; o[2] = (__bf16)v.z; o[3] = (__bf16)v.w;
    ((bf16x4*)xb)[i] = o;
}

// ------------------------------------- P (512x8000) -> P_t bf16 (8000x512) -
// P_t[j][d] = P[d][j] / max(sqrt(ssq[j]),1e-12)
__global__ __launch_bounds__(256) void k_tpose(const float* __restrict__ P,
                                               const float* __restrict__ ssq,
                                               __bf16* __restrict__ Pt) {
    __shared__ float t[64][65];
    int tid = threadIdx.x;
    int tx = tid & 63, ty = tid >> 6;
    int j0 = blockIdx.x * 64, d0 = blockIdx.y * 64;
#pragma unroll
    for (int r = 0; r < 16; ++r) {
        int d = d0 + ty * 16 + r;
        t[ty * 16 + r][tx] = P[(size_t)d * PCN + j0 + tx];
    }
    __syncthreads();
#pragma unroll
    for (int r = 0; r < 16; ++r) {
        int jl = ty * 16 + r;
        float iv = 1.0f / fmaxf(sqrtf(ssq[j0 + jl]), 1e-12f);
        Pt[(size_t)(j0 + jl) * PDIM + d0 + tx] = (__bf16)(t[tx][jl] * iv);
    }
}

// --------------------------------------------- ccls bf16 (1024x512) -------
__global__ __launch_bounds__(256) void k_ccls(const __bf16* __restrict__ Pt,
                                              __bf16* __restrict__ ccls) {
    int idx = blockIdx.x * 256 + threadIdx.x;
    int d = idx & 511, c = idx >> 9;
    float s = 0.f;
    if (c < PC) {
#pragma unroll
        for (int n = 0; n < 8; ++n)
            s += (float)Pt[(size_t)(c * 8 + n) * PDIM + d];
    }
    ccls[idx] = (__bf16)s;
}

// ---------------------------------------------------------------- GEMM ----
// out[m][j] = sum_d A[m][d]*Bt[j][d]; grid.x over j (Bt rows), grid.y over m.
__global__ __launch_bounds__(256) void k_gemm(const __bf16* __restrict__ A,
                                              const __bf16* __restrict__ Bt,
                                              float* __restrict__ out,
                                              int Ma, int Mstore,
                                              int Nb, int Nstore, int ldo) {
    __shared__ __bf16 As[128 * 32];
    __shared__ __bf16 Bs[128 * 32];
    int tid = threadIdx.x;
    int w = tid >> 6, lane = tid & 63;
    int wr = w >> 1, wc = w & 1;
    int quad = lane >> 4, l15 = lane & 15;
    int n0 = blockIdx.x * 128, m0 = blockIdx.y * 128;
    f32x4 acc[4][4] = {};
    for (int k0 = 0; k0 < PDIM; k0 += 32) {
#pragma unroll
        for (int pass = 0; pass < 2; ++pass) {
            int cbase = pass * 256 + w * 64;
            int c = cbase + lane;
            int arow = m0 + (c >> 2);
            if (arow > Ma - 1) arow = Ma - 1;
            async_load16(A + (size_t)arow * PDIM + k0 + (c & 3) * 8, &As[cbase * 8]);
            int brow = n0 + (c >> 2);
            if (brow > Nb - 1) brow = Nb - 1;
            async_load16(Bt + (size_t)brow * PDIM + k0 + (c & 3) * 8, &Bs[cbase * 8]);
        }
        __syncthreads();
        bf16x8 av[4], bv[4];
#pragma unroll
        for (int i = 0; i < 4; ++i) {
            av[i] = *(const bf16x8*)&As[(wr * 64 + i * 16 + l15) * 32 + quad * 8];
            bv[i] = *(const bf16x8*)&Bs[(wc * 64 + i * 16 + l15) * 32 + quad * 8];
        }
#pragma unroll
        for (int i = 0; i < 4; ++i)
#pragma unroll
            for (int j = 0; j < 4; ++j)
                acc[i][j] = __builtin_amdgcn_mfma_f32_16x16x32_bf16(
                    av[i], bv[j], acc[i][j], 0, 0, 0);
        __syncthreads();
    }
#pragma unroll
    for (int i = 0; i < 4; ++i) {
        int r0 = m0 + wr * 64 + i * 16 + quad * 4;
#pragma unroll
        for (int j = 0; j < 4; ++j) {
            int cc = n0 + wc * 64 + j * 16 + l15;
            if (cc < Nstore) {
#pragma unroll
                for (int r = 0; r < 4; ++r) {
                    int rr = r0 + r;
                    if (rr < Mstore) out[(size_t)rr * ldo + cc] = acc[i][j][r];
                }
            }
        }
    }
}

// ------------------------------------------------------------- row loss ---
// Linear-quantized 1024-bin histogram select for tau, then softmax loss.
__global__ __launch_bounds__(256) void k_rowloss(const float* __restrict__ sim,
                                                 const int* __restrict__ target,
                                                 float* __restrict__ acc) {
    __shared__ __align__(16) float s[PCN];
    __shared__ unsigned hist[NBIN];
    __shared__ unsigned tsum[256];
    __shared__ float cand[CANDMAX];
    __shared__ unsigned candn;
    __shared__ float redf[8];
    __shared__ float s_lo, s_scale;
    __shared__ int s_bin, s_A;
    __shared__ float s_tau;
    __shared__ int s_gt, s_eq;
    __shared__ float s_et;

    int b = blockIdx.x, tid = threadIdx.x;
    const float* row = sim + (size_t)b * PCN;
    int targ = target[b];

    // load row (vectorized), keep register copy, track nonpos min/max
    float4 v4[8];
    float lmn = INFINITY, lmx = -INFINITY;
#pragma unroll
    for (int k = 0; k < 8; ++k) {
        int i4 = tid + 256 * k;            // < 2000 valid
        if (i4 < PCN / 4) {
            float4 val = ((const float4*)row)[i4];
            v4[k] = val;
            ((float4*)s)[i4] = val;
            int j = i4 * 4;
            if ((j >> 3) != targ) {        // all 4 share class (j..j+3, same j>>3)
                lmn = fminf(lmn, fminf(fminf(val.x, val.y), fminf(val.z, val.w)));
                lmx = fmaxf(lmx, fmaxf(fmaxf(val.x, val.y), fmaxf(val.z, val.w)));
            }
        } else {
            v4[k] = make_float4(0.f, 0.f, 0.f, 0.f);
        }
    }
    for (int off = 32; off; off >>= 1) {
        lmn = fminf(lmn, __shfl_down(lmn, off, 64));
        lmx = fmaxf(lmx, __shfl_down(lmx, off, 64));
    }
    if ((tid & 63) == 0) { redf[tid >> 6] = lmn; redf[4 + (tid >> 6)] = lmx; }
    // init hist while waiting
#pragma unroll
    for (int k = 0; k < 4; ++k) hist[tid + 256 * k] = 0u;
    if (tid == 0) candn = 0u;
    __syncthreads();
    if (tid == 0) {
        float lo = fminf(fminf(redf[0], redf[1]), fminf(redf[2], redf[3]));
        float hi = fmaxf(fmaxf(redf[4], redf[5]), fmaxf(redf[6], redf[7]));
        s_lo = lo;
        float range = hi - lo;
        s_scale = (range > 0.f) ? (float)NBIN / range : 0.f;
    }
    __syncthreads();
    float lo = s_lo, scale = s_scale;

    // histogram from registers
#pragma unroll
    for (int k = 0; k < 8; ++k) {
        int i4 = tid + 256 * k;
        if (i4 < PCN / 4 && ((i4 * 4) >> 3) != targ) {
            float pv[4] = {v4[k].x, v4[k].y, v4[k].z, v4[k].w};
#pragma unroll
            for (int q = 0; q < 4; ++q) {
                int bin = (int)((pv[q] - lo) * scale);
                bin = bin < 0 ? 0 : (bin > NBIN - 1 ? NBIN - 1 : bin);
                atomicAdd(&hist[bin], 1u);
            }
        }
    }
    __syncthreads();

    // suffix scan: local over 4 bins + 256-wide Hillis-Steele suffix
    int b0 = tid * 4;
    unsigned h0 = hist[b0], h1 = hist[b0 + 1], h2 = hist[b0 + 2], h3 = hist[b0 + 3];
    unsigned l3 = h3, l2 = h2 + l3, l1 = h1 + l2, l0 = h0 + l1;
    tsum[tid] = l0;
    __syncthreads();
    for (int step = 1; step < 256; step <<= 1) {
        unsigned x = (tid + step < 256) ? tsum[tid + step] : 0u;
        __syncthreads();
        tsum[tid] += x;
        __syncthreads();
    }
    unsigned tail = (tid < 255) ? tsum[tid + 1] : 0u;
    {
        unsigned sfx[4] = {l0 + tail, l1 + tail, l2 + tail, l3 + tail};
        unsigned nxt[4] = {l1 + tail, l2 + tail, l3 + tail, tail};
#pragma unroll
        for (int i = 0; i < 4; ++i)
            if (sfx[i] >= NONPOS_K && nxt[i] < NONPOS_K) {
                s_bin = b0 + i;
                s_A = (int)nxt[i];
            }
    }
    __syncthreads();
    int tbin = s_bin, A = s_A;

    // collect candidates in tau's bin
#pragma unroll
    for (int k = 0; k < 8; ++k) {
        int i4 = tid + 256 * k;
        if (i4 < PCN / 4 && ((i4 * 4) >> 3) != targ) {
            float pv[4] = {v4[k].x, v4[k].y, v4[k].z, v4[k].w};
#pragma unroll
            for (int q = 0; q < 4; ++q) {
                int bin = (int)((pv[q] - lo) * scale);
                bin = bin < 0 ? 0 : (bin > NBIN - 1 ? NBIN - 1 : bin);
                if (bin == tbin) {
                    unsigned idx = atomicAdd(&candn, 1u);
                    if (idx < CANDMAX) cand[idx] = pv[q];
                }
            }
        }
    }
    __syncthreads();
    int m = (int)candn; if (m > CANDMAX) m = CANDMAX;
    int rank = NONPOS_K - A;               // 1-based rank within the bin
    if (tid < m) {
        float val = cand[tid];
        int g = 0, e = 0;
        for (int i = 0; i < m; ++i) {
            g += cand[i] > val;
            e += cand[i] == val;
        }
        if (g < rank && rank <= g + e) { s_tau = val; s_gt = g; s_eq = e; }
    }
    __syncthreads();
    float tau = s_tau;
    int cgt = A + s_gt;                    // global strictly-greater count
    int ceq = s_eq;                        // global equal count
    int rem = NONPOS_K - cgt;              // equals to include, by index order
    bool all_eq = (rem >= ceq);

    // per-class logits -> exp -> loss
    float psum = 0.f;
    for (int c = tid; c < PC; c += 256) {
        float lg = 0.f;
        float4 p0 = *(const float4*)&s[c * 8];
        float4 p1 = *(const float4*)&s[c * 8 + 4];
        float pv[8] = {p0.x, p0.y, p0.z, p0.w, p1.x, p1.y, p1.z, p1.w};
        if (c == targ) {
#pragma unroll
            for (int n = 0; n < 8; ++n) lg += pv[n];
        } else {
#pragma unroll
            for (int n = 0; n < 8; ++n) {
                float v = pv[n];
                bool sel = v > tau;
                if (!sel && v == tau) {
                    if (all_eq) sel = true;
                    else {                  // rare exact-tie path
                        int rk = 0, j = c * 8 + n;
                        for (int jj = 0; jj < j; ++jj)
                            rk += ((jj >> 3) != targ && s[jj] == tau) ? 1 : 0;
                        sel = (rk < rem);
                    }
                }
                if (sel) lg += v;
            }
        }
        float e = (lg != 0.0f) ? expf(lg) : 0.0f;
        psum += e;
        if (c == targ) s_et = e;
    }
    for (int off = 32; off; off >>= 1) psum += __shfl_down(psum, off, 64);
    if ((tid & 63) == 0) redf[tid >> 6] = psum;
    __syncthreads();
    if (tid == 0) {
        float denom = 1e-8f + redf[0] + redf[1] + redf[2] + redf[3];
        atomicAdd(acc, -logf(s_et / denom + 1e-20f));
    }
}

// ------------------------------------------------------------- reg --------
// clog (8000 x 1000) row-major: one wave per row
__global__ __launch_bounds__(256) void k_reg(const float* __restrict__ clog,
                                             float* __restrict__ acc) {
    __shared__ float part[4];
    int wv = threadIdx.x >> 6, lane = threadIdx.x & 63;
    int j = blockIdx.x * 4 + wv;           // 2000 blocks
    const float* row = clog + (size_t)j * PC;
    float v[16];
    float mx = -INFINITY;
#pragma unroll
    for (int k = 0; k < 16; ++k) {
        int c = lane + k * 64;
        v[k] = (c < PC) ? row[c] : -INFINITY;
        mx = fmaxf(mx, v[k]);
    }
    for (int off = 32; off; off >>= 1) mx = fmaxf(mx, __shfl_down(mx, off, 64));
    mx = __shfl(mx, 0, 64);
    float sum = 0.f;
#pragma unroll
    for (int k = 0; k < 16; ++k)
        if (lane + k * 64 < PC) sum += expf(v[k] - mx);
    for (int off = 32; off; off >>= 1) sum += __shfl_down(sum, off, 64);
    if (lane == 0) part[wv] = logf(sum) + mx - row[j >> 3];
    __syncthreads();
    if (threadIdx.x == 0)
        atomicAdd(acc + 1, part[0] + part[1] + part[2] + part[3]);
}

// --------------------------------------------------------------- final ----
__global__ void k_final(const float* __restrict__ acc, float* __restrict__ out) {
    float lc = acc[0] * (1.0f / PB);
    float rg = acc[1] * (1.0f / PCN);
    out[0] = lc + 0.3f * rg;
    out[1] = lc;
}

// ---------------------------------------------------------------------------
extern "C" void kernel_launch(void* const* d_in, const int* in_sizes, int n_in,
                              void* d_out, int out_size, void* d_ws, size_t ws_size,
                              hipStream_t stream) {
    const float* x       = (const float*)d_in[0];   // (1024, 512)
    const float* proxies = (const float*)d_in[1];   // (512, 8000)
    const int*   target  = (const int*)d_in[2];     // (1024,)
    float* out = (float*)d_out;
    float* ws  = (float*)d_ws;

    // workspace layout (float offsets)
    float*  acc   = ws;                       // [2]
    float*  ssq   = ws + 64;                  // [8000]
    __bf16* xb    = (__bf16*)(ws + 8256);     // 1024x512 bf16
    __bf16* cclsb = (__bf16*)(ws + 270400);   // 1024x512 bf16
    __bf16* Pt    = (__bf16*)(ws + 532544);   // 8000x512 bf16
    float*  big   = ws + 2580544;             // 1024x8000 f32 sim / 8000x1000 clog
    // total: 10,772,544 floats = 41.1 MiB

    hipMemsetAsync(ws, 0, (64 + 8000) * sizeof(float), stream);

    k_norm_part<<<dim3(32, 8), 256, 0, stream>>>(proxies, ssq);
    k_xconv<<<512, 256, 0, stream>>>(x, xb);
    k_tpose<<<dim3(125, 8), 256, 0, stream>>>(proxies, ssq, Pt);
    k_ccls<<<2048, 256, 0, stream>>>(Pt, cclsb);

    // sim (1024 x 8000)
    k_gemm<<<dim3(63, 8), 256, 0, stream>>>(xb, Pt, big, PB, PB, PCN, PCN, PCN);
    k_rowloss<<<PB, 256, 0, stream>>>(big, target, acc);

    // clog (8000 x 1000): A=Pt (M=8000), B=ccls (N=1024, store 1000)
    k_gemm<<<dim3(8, 63), 256, 0, stream>>>(Pt, cclsb, big, PCN, PCN, PB, PC, PC);
    k_reg<<<2000, 256, 0, stream>>>(big, acc);

    k_final<<<1, 1, 0, stream>>>(acc, out);
}